// Round 6
// baseline (292.144 us; speedup 1.0000x reference)
//
#include <hip/hip_runtime.h>
#include <math.h>

// SIFA fused, MFMA v8.
// v7 (236.7us) left k_conv as the largest kernel (81us, latency-bound:
// VALU 48%, 2.2TB/s, occupancy 47%). Cause: the 22.5KB per-thread `ul` LDS
// staging (cell assembly from j-pairs) caps residency at 5 blocks/CU and is
// the latency chain + bank-conflict source. v8 deletes `ul`: the j-loop is
// restructured per-CELL (ci=0..4); each cell's j-even quad (40 live uniform
// scalars, v7-proven budget) fills oc.x/oc.y, j-odd fills oc.z/oc.w, then
// ONE dense uint4 store from registers. LDS 28.2KB -> 5.6KB (8 blocks/CU).
// k_fold/k_gate/k_main byte-identical to v7.

#define EPSF 1e-5f
typedef _Float16 v8h __attribute__((ext_vector_type(8)));
typedef __fp16 fp16x2 __attribute__((ext_vector_type(2)));   // cvt_pkrtz native type
typedef float v4f __attribute__((ext_vector_type(4)));

static constexpr int C_ = 64, HW_ = 16384, W_ = 128;
static constexpr int KB_ = 80;                 // K = 640 = 80 cells of 8 f16

// ws float offsets
static constexpr int WS_WFOLD = 0;       // 5184: [c][j][k] folded depthwise weights
static constexpr int WS_SHIFT = 5184;    // 576
static constexpr int WS_BIAS  = 5760;    // 128
static constexpr int WS_GATE  = 5888;    // 512*4 {wa*cgate, 1-wa, -log2e*a_sp, -log2e*b_sp}
static constexpr int WS_PART  = 7936;    // 8b*16cq*8(ch*2+s)*64p = 65536
static constexpr int WS_WH    = 73472;   // 80*128*8 f16 = 40960 floats: Wh[kb][oup][8]
static constexpr int WS_BIMG  = 114688;  // B-image: per batch 128tile*80kb*128px*8 f16
static constexpr size_t BIMG_BATCH_F16 = (size_t)128 * KB_ * 128 * 8;   // 10,485,760
static constexpr size_t BIMG_BATCH_FLT = BIMG_BATCH_F16 / 2;            // 5,242,880

__device__ __forceinline__ float sigmf(float v) { return 1.f / (1.f + __expf(-v)); }

__device__ __forceinline__ unsigned int pk_u32(float a, float b) {
    fp16x2 h = __builtin_amdgcn_cvt_pkrtz(a, b);
    return __builtin_bit_cast(unsigned int, h);
}

// K-slot map: k = grp*80 + tp*40 + vv; grp=c>>3, tp=(c>>2)&1, vv=j*4+(c&3)
// (vv 36..39 zero pads). Cell kb=k>>3 has block-constant channel quad
// cbase = grp*8+tp*4, element e: c = cbase+(e&3), j = 2*(kb%5)+(e>>2).
__global__ __launch_bounds__(256) void k_fold(
    const float* __restrict__ gen_w,
    const float* __restrict__ gg, const float* __restrict__ gb,
    const float* __restrict__ gm, const float* __restrict__ gv,
    const float* __restrict__ conv_w,
    const float* __restrict__ cg, const float* __restrict__ cb,
    const float* __restrict__ cm, const float* __restrict__ cv,
    float* __restrict__ ws)
{
    int idx = blockIdx.x * 256 + threadIdx.x;
    _Float16* Whp = (_Float16*)(ws + WS_WH);
    if (idx < 81920) {
        // fragment layout: idx = (kb*128 + oup)*8 + e; K index k = kb*8+e
        int kb = idx >> 10, oup = (idx >> 3) & 127, e = idx & 7;
        int k = kb * 8 + e;
        int grp = k / 80, rr = k - grp * 80;
        int tp = rr / 40, vv = rr - tp * 40;
        float v = 0.f;
        if (vv < 36) {
            int j = vv >> 2, cl = vv & 3, c = grp * 8 + tp * 4 + cl;
            float s = cg[oup] * rsqrtf(cv[oup] + EPSF);
            v = conv_w[(oup * C_ + c) * 9 + j] * s;
        }
        Whp[idx] = (_Float16)v;
    } else if (idx < 87104) {
        int i = idx - 81920; int ce = i / 9;
        float s = gg[ce] * rsqrtf(gv[ce] + EPSF);
        ws[WS_WFOLD + i] = gen_w[i] * s;
    } else if (idx < 87680) {
        int ce = idx - 87104;
        float s = gg[ce] * rsqrtf(gv[ce] + EPSF);
        ws[WS_SHIFT + ce] = gb[ce] - gm[ce] * s;
    } else if (idx < 87808) {
        int oup = idx - 87680;
        float s = cg[oup] * rsqrtf(cv[oup] + EPSF);
        ws[WS_BIAS + oup] = cb[oup] - cm[oup] * s;
    }
}

// nb*1024 blocks: (bbl, p(64), cq(16)). Thread owns 1 px of a 16x16 region,
// 4 channels. Conv+relu ONCE; per-CELL register assembly (j-even then j-odd
// sub-blocks, each <=40 live uniform scalars), ONE dense uint4 store per
// cell (5 total); block-reduced sum/sumsq partials. No ul LDS (v8).
__global__ __launch_bounds__(256) void k_conv(
    const float* __restrict__ x, float* __restrict__ ws, int b0)
{
    __shared__ float xs[4][18 * 19];
    __shared__ float red[4][8];
    int bid = blockIdx.x;
    int cq = bid & 15, p = (bid >> 4) & 63, bbl = bid >> 10;
    int b = b0 + bbl;
    int oh0 = (p >> 3) << 4, ow0 = (p & 7) << 4;
    int t = threadIdx.x;
    int row16 = t >> 4, col = t & 15;

    for (int i = t; i < 1296; i += 256) {
        int ch = i / 324, rr = i - ch * 324;
        int r = rr / 18, cc = rr - r * 18;
        int yy = oh0 + r - 1, xx = ow0 + cc - 1;
        float v = 0.f;
        if (yy >= 0 && yy < 128 && xx >= 0 && xx < 128)
            v = x[(size_t)(b * C_ + cq * 4 + ch) * HW_ + yy * 128 + xx];
        xs[ch][r * 19 + cc] = v;
    }
    __syncthreads();

    float nb4[4][9];
#pragma unroll
    for (int ch = 0; ch < 4; ++ch)
#pragma unroll
        for (int dy = 0; dy < 3; ++dy)
#pragma unroll
            for (int dx = 0; dx < 3; ++dx)
                nb4[ch][dy * 3 + dx] = xs[ch][(row16 + dy) * 19 + col + dx];

    float st[8];                              // st[ch*2] = sum, st[ch*2+1] = sumsq
#pragma unroll
    for (int k = 0; k < 8; ++k) st[k] = 0.f;

    int tile = ((p >> 3) * 2 + (row16 >> 3)) * 8 + (p & 7);
    int px = (row16 & 7) * 16 + col;
    int kbBase = (cq >> 1) * 10 + (cq & 1) * 5;
    _Float16* Bimg = (_Float16*)(ws + WS_BIMG) + (size_t)bbl * BIMG_BATCH_F16;

#pragma unroll 1
    for (int ci = 0; ci < 5; ++ci) {          // cell = {j=2ci (e0..3), j=2ci+1 (e4..7)}
        uint4 oc;
        {   // ---- j even: <=40 live uniform scalars (v7-proven budget)
            int j = 2 * ci;
            float wj[4][9], sj[4];
#pragma unroll
            for (int ch = 0; ch < 4; ++ch) {
                const float* wp = ws + WS_WFOLD + (cq * 4 + ch) * 81 + j * 9;
#pragma unroll
                for (int k = 0; k < 9; ++k) wj[ch][k] = wp[k];
                sj[ch] = ws[WS_SHIFT + (cq * 4 + ch) * 9 + j];
            }
            float uv[4];
#pragma unroll
            for (int ch = 0; ch < 4; ++ch) {
                float a = sj[ch];
#pragma unroll
                for (int k = 0; k < 9; ++k) a = fmaf(wj[ch][k], nb4[ch][k], a);
                float v = fmaxf(a, 0.f);
                uv[ch] = v;
                st[ch * 2] += v;
                st[ch * 2 + 1] = fmaf(v, v, st[ch * 2 + 1]);
            }
            oc.x = pk_u32(uv[0], uv[1]);
            oc.y = pk_u32(uv[2], uv[3]);
        }
        if (ci < 4) {   // ---- j odd
            int j = 2 * ci + 1;
            float wj[4][9], sj[4];
#pragma unroll
            for (int ch = 0; ch < 4; ++ch) {
                const float* wp = ws + WS_WFOLD + (cq * 4 + ch) * 81 + j * 9;
#pragma unroll
                for (int k = 0; k < 9; ++k) wj[ch][k] = wp[k];
                sj[ch] = ws[WS_SHIFT + (cq * 4 + ch) * 9 + j];
            }
            float uv[4];
#pragma unroll
            for (int ch = 0; ch < 4; ++ch) {
                float a = sj[ch];
#pragma unroll
                for (int k = 0; k < 9; ++k) a = fmaf(wj[ch][k], nb4[ch][k], a);
                float v = fmaxf(a, 0.f);
                uv[ch] = v;
                st[ch * 2] += v;
                st[ch * 2 + 1] = fmaf(v, v, st[ch * 2 + 1]);
            }
            oc.z = pk_u32(uv[0], uv[1]);
            oc.w = pk_u32(uv[2], uv[3]);
        } else {        // cell 4: e4..7 are zero pads (vv 36..39)
            oc.z = 0u; oc.w = 0u;
        }
        *(uint4*)(Bimg + (size_t)(tile * KB_ + kbBase + ci) * 1024 + (size_t)px * 8) = oc;
    }

    // ---- stats: wave shuffle reduce, then cross-wave via tiny LDS
#pragma unroll
    for (int off = 32; off > 0; off >>= 1)
#pragma unroll
        for (int k = 0; k < 8; ++k) st[k] += __shfl_down(st[k], off, 64);
    int w = t >> 6, lane = t & 63;
    if (lane == 0)
#pragma unroll
        for (int k = 0; k < 8; ++k) red[w][k] = st[k];
    __syncthreads();
    if (t < 8) {
        float v = red[0][t] + red[1][t] + red[2][t] + red[3][t];
        float* part = ws + WS_PART;
        part[(size_t)((b * 16 + cq) * 8 + t) * 64 + p] = v;
    }
}

__global__ __launch_bounds__(256) void k_gate(
    const float* __restrict__ part,
    const float* __restrict__ cwt, const float* __restrict__ cbs,
    const float* __restrict__ swt, const float* __restrict__ sbs,
    const float* __restrict__ gnw, const float* __restrict__ gnb,
    const float* __restrict__ wadd, float4* __restrict__ gate, int b0, int nb)
{
    int i = blockIdx.x * 256 + threadIdx.x;
    if (i >= nb * 64) return;
    int b = b0 + (i >> 6), c = i & 63;
    const float* pp = part + (size_t)((b * 16 + (c >> 2)) * 8 + (c & 3) * 2) * 64;
    float s1 = 0.f, s2 = 0.f;
#pragma unroll
    for (int q = 0; q < 16; ++q) {
        float4 a = *(const float4*)(pp + q * 4);
        float4 d = *(const float4*)(pp + 64 + q * 4);
        s1 += a.x + a.y + a.z + a.w;
        s2 += d.x + d.y + d.z + d.w;
    }
    const float N = 9.f * 16384.f;
    float mean = s1 / N;
    float var = s2 / N - mean * mean;
    float inv = rsqrtf(var + EPSF);
    int cgi = c & 7;
    float wa = wadd[0];
    float cgt = sigmf(cwt[cgi] * mean + cbs[cgi]);
    const float NL2E = -1.44269504f;   // sigm(t)=rcp(1+exp2(-t*log2e))
    float4 o;
    o.x = wa * cgt;
    o.y = 1.f - wa;
    o.z = NL2E * (swt[cgi] * gnw[cgi] * inv);
    o.w = NL2E * (swt[cgi] * (gnb[cgi] - mean * inv * gnw[cgi]) + sbs[cgi]);
    gate[b * 64 + c] = o;
}

// nb*256 blocks: (bbl, tile, half). M=128 oup x N=64 px, K=640 in 2 rounds of
// 40 cells. Staging phase gates the pre-gate B-image into kb-major LDS
// Bs[40][64][8] (40KB); MFMA phase: wave w owns 32-oup slab, B shared by all
// waves from LDS. Gate cost paid once per element; gate(0)=0 keeps pads.
__global__ __launch_bounds__(256, 4) void k_main(
    const float* __restrict__ ws, float* __restrict__ out, int b0)
{
    __shared__ _Float16 Bs[40 * 512];      // [kl][px(64)][8] = 40 KB
    int t = threadIdx.x;
    int bid = blockIdx.x;
    int half = bid & 1, tile = (bid >> 1) & 127, bbl = bid >> 8;
    int b = b0 + bbl;
    int oh0 = (tile >> 3) << 3, ow0 = (tile & 7) << 4;

    int w = __builtin_amdgcn_readfirstlane(t >> 6);
    int lane = t & 63, quad = lane >> 4, l15 = lane & 15;

    const _Float16* Wh = (const _Float16*)(ws + WS_WH);
    const _Float16* Bimg = (const _Float16*)(ws + WS_BIMG)
        + (size_t)bbl * BIMG_BATCH_F16 + (size_t)tile * (KB_ * 1024)
        + (size_t)(half * 64 + lane) * 8;
    const float4* gp = (const float4*)(ws + WS_GATE) + b * 64;

    v4f acc[2][4];
#pragma unroll
    for (int a = 0; a < 2; ++a)
#pragma unroll
        for (int bb = 0; bb < 4; ++bb) acc[a][bb] = (v4f)0.f;

#pragma unroll 1
    for (int r = 0; r < 2; ++r) {
        if (r) __syncthreads();            // MFMA of prev round done reading Bs
        // ---- stage + gate: 40 cells, 10 per wave, 1KB/wave coalesced loads
#pragma unroll 2
        for (int i = 0; i < 10; ++i) {
            int kl = i * 4 + w;            // wave-uniform LDS cell
            int kb = r * 40 + kl;          // wave-uniform global cell
            int q5 = kb / 10;
            int cbase = q5 * 8 + (kb - q5 * 10 >= 5 ? 4 : 0);
            float4 g0 = gp[cbase], g1 = gp[cbase + 1];
            float4 g2 = gp[cbase + 2], g3 = gp[cbase + 3];
            uint4 cell = *(const uint4*)(Bimg + (size_t)kb * 1024);
            v8h v = __builtin_bit_cast(v8h, cell);
            float u[8];
#pragma unroll
            for (int e = 0; e < 8; ++e) {
                float f = (float)v[e];
                float4 g = (e & 3) == 0 ? g0 : ((e & 3) == 1 ? g1 : ((e & 3) == 2 ? g2 : g3));
                float ex = __builtin_amdgcn_exp2f(fmaf(g.z, f, g.w));
                u[e] = f * fmaf(g.y, __builtin_amdgcn_rcpf(1.f + ex), g.x);
            }
            uint4 oc;
            oc.x = pk_u32(u[0], u[1]); oc.y = pk_u32(u[2], u[3]);
            oc.z = pk_u32(u[4], u[5]); oc.w = pk_u32(u[6], u[7]);
            *(uint4*)(Bs + kl * 512 + lane * 8) = oc;   // contiguous 1KB/wave
        }
        __syncthreads();
        // ---- MFMA: 10 K-steps of 32; A from L2-hot Wh, B from LDS
#pragma unroll
        for (int s = 0; s < 10; ++s) {
            int cglob = r * 40 + s * 4 + quad;
            const _Float16* Ap = Wh + ((size_t)cglob * 128 + w * 32 + l15) * 8;
            v8h A0 = *(const v8h*)(Ap);
            v8h A1 = *(const v8h*)(Ap + 128);          // +16 oup rows
            int klq = s * 4 + quad;
            v8h Bf[4];
#pragma unroll
            for (int bb = 0; bb < 4; ++bb)
                Bf[bb] = *(const v8h*)(Bs + klq * 512 + (bb * 16 + l15) * 8);
#pragma unroll
            for (int bb = 0; bb < 4; ++bb) {
                acc[0][bb] = __builtin_amdgcn_mfma_f32_16x16x32_f16(A0, Bf[bb], acc[0][bb], 0, 0, 0);
                acc[1][bb] = __builtin_amdgcn_mfma_f32_16x16x32_f16(A1, Bf[bb], acc[1][bb], 0, 0, 0);
            }
        }
    }

    // ---- epilogue: bias + SiLU; C/D: col=lane&15(px), row=quad*4+reg(oup)
    size_t ob = (size_t)b * 128 * HW_;
#pragma unroll
    for (int a = 0; a < 2; ++a) {
#pragma unroll
        for (int r2 = 0; r2 < 4; ++r2) {
            int oup = w * 32 + a * 16 + quad * 4 + r2;
            float bo = ws[WS_BIAS + oup];
#pragma unroll
            for (int bb = 0; bb < 4; ++bb) {
                int p2 = half * 64 + bb * 16 + l15;
                int py2 = p2 >> 4, px2 = p2 & 15;
                float z = acc[a][bb][r2] + bo;
                out[ob + (size_t)oup * HW_ + (oh0 + py2) * W_ + ow0 + px2] = z * sigmf(z);
            }
        }
    }
}

extern "C" void kernel_launch(void* const* d_in, const int* in_sizes, int n_in,
                              void* d_out, int out_size, void* d_ws, size_t ws_size,
                              hipStream_t stream)
{
    const float* x      = (const float*)d_in[0];
    const float* gen_w  = (const float*)d_in[1];
    const float* gg     = (const float*)d_in[2];
    const float* gb     = (const float*)d_in[3];
    const float* gm     = (const float*)d_in[4];
    const float* gv     = (const float*)d_in[5];
    const float* gnw    = (const float*)d_in[6];
    const float* gnb    = (const float*)d_in[7];
    const float* cwt    = (const float*)d_in[8];
    const float* cbs    = (const float*)d_in[9];
    const float* swt    = (const float*)d_in[10];
    const float* sbs    = (const float*)d_in[11];
    const float* wadd   = (const float*)d_in[12];
    const float* conv_w = (const float*)d_in[13];
    const float* cg2    = (const float*)d_in[14];
    const float* cb2    = (const float*)d_in[15];
    const float* cm2    = (const float*)d_in[16];
    const float* cv2    = (const float*)d_in[17];
    float* ws  = (float*)d_ws;
    float* out = (float*)d_out;

    // pick the largest batch chunk whose B-image fits in ws
    size_t avail = ws_size / 4;   // floats
    int nb = 1;
    const int cands[4] = {8, 4, 2, 1};
    for (int i = 0; i < 4; ++i) {
        if ((size_t)WS_BIMG + (size_t)cands[i] * BIMG_BATCH_FLT <= avail) { nb = cands[i]; break; }
    }

    k_fold<<<343, 256, 0, stream>>>(gen_w, gg, gb, gm, gv, conv_w, cg2, cb2, cm2, cv2, ws);
    for (int b0 = 0; b0 < 8; b0 += nb) {
        k_conv<<<nb * 1024, 256, 0, stream>>>(x, ws, b0);
        k_gate<<<(nb * 64 + 255) / 256, 256, 0, stream>>>(
            ws + WS_PART, cwt, cbs, swt, sbs, gnw, gnb, wadd,
            (float4*)(ws + WS_GATE), b0, nb);
        k_main<<<nb * 256, 256, 0, stream>>>(ws, out, b0);
    }
}

// Round 7
// 241.266 us; speedup vs baseline: 1.2109x; 1.2109x over previous
//
#include <hip/hip_runtime.h>
#include <math.h>

// SIFA fused, MFMA v9.
// v8 failed via SGPR demotion (SGPR 112->32: compiler dropped s_loads for
// uniform weights -> per-lane VMEM chains, k_conv 81->141us). v9 uses the
// v3-proven robust pattern: weights REGISTER-RESIDENT (wv[81]+sh9[9] per
// thread, copied once from LDS, static indexing). Wave = channel, thread =
// 4 px (rows r0+4i) -> every B-image store is a dense 1KB/wave line.
// B-image cell map re-keyed channel-major: cell kbBase+cl (cl<4) = channel
// cbase+cl with j=e; cell kbBase+4 = 4 channels' j=8 (+pads) via 2KB LDS
// exchange. k_fold + k_main staging updated to the map (k_main gate params
// now cell-uniform for 4/5 cells). MFMA/epilogue/k_gate untouched.

#define EPSF 1e-5f
typedef _Float16 v8h __attribute__((ext_vector_type(8)));
typedef __fp16 fp16x2 __attribute__((ext_vector_type(2)));   // cvt_pkrtz native type
typedef float v4f __attribute__((ext_vector_type(4)));

static constexpr int C_ = 64, HW_ = 16384, W_ = 128;
static constexpr int KB_ = 80;                 // K = 640 = 80 cells of 8 f16

// ws float offsets
static constexpr int WS_WFOLD = 0;       // 5184: [c][j][k] folded depthwise weights
static constexpr int WS_SHIFT = 5184;    // 576
static constexpr int WS_BIAS  = 5760;    // 128
static constexpr int WS_GATE  = 5888;    // 512*4 {wa*cgate, 1-wa, -log2e*a_sp, -log2e*b_sp}
static constexpr int WS_PART  = 7936;    // 8b*16cq*8(ch*2+s)*64p = 65536
static constexpr int WS_WH    = 73472;   // 80*128*8 f16 = 40960 floats: Wh[kb][oup][8]
static constexpr int WS_BIMG  = 114688;  // B-image: per batch 128tile*80kb*128px*8 f16
static constexpr size_t BIMG_BATCH_F16 = (size_t)128 * KB_ * 128 * 8;   // 10,485,760
static constexpr size_t BIMG_BATCH_FLT = BIMG_BATCH_F16 / 2;            // 5,242,880

__device__ __forceinline__ float sigmf(float v) { return 1.f / (1.f + __expf(-v)); }

__device__ __forceinline__ unsigned int pk_u32(float a, float b) {
    fp16x2 h = __builtin_amdgcn_cvt_pkrtz(a, b);
    return __builtin_bit_cast(unsigned int, h);
}

// K-slot map (v9, channel-major cells): kb in [0,80): grp=kb/10, r=kb%10,
// tp=r/5, cl=r%5, cbase=grp*8+tp*4.
//   cl<4 : cell = channel cbase+cl, j = e (e=0..7)
//   cl==4: e<4 -> channel cbase+e, j=8 ; e>=4 -> zero pad
__global__ __launch_bounds__(256) void k_fold(
    const float* __restrict__ gen_w,
    const float* __restrict__ gg, const float* __restrict__ gb,
    const float* __restrict__ gm, const float* __restrict__ gv,
    const float* __restrict__ conv_w,
    const float* __restrict__ cg, const float* __restrict__ cb,
    const float* __restrict__ cm, const float* __restrict__ cv,
    float* __restrict__ ws)
{
    int idx = blockIdx.x * 256 + threadIdx.x;
    _Float16* Whp = (_Float16*)(ws + WS_WH);
    if (idx < 81920) {
        // fragment layout: idx = (kb*128 + oup)*8 + e
        int kb = idx >> 10, oup = (idx >> 3) & 127, e = idx & 7;
        int grp = kb / 10, r = kb - grp * 10;
        int tp = r / 5, cl = r - tp * 5;
        int cbase = grp * 8 + tp * 4;
        int c = -1, j = 0;
        if (cl < 4) { c = cbase + cl; j = e; }
        else if (e < 4) { c = cbase + e; j = 8; }
        float v = 0.f;
        if (c >= 0) {
            float s = cg[oup] * rsqrtf(cv[oup] + EPSF);
            v = conv_w[(oup * C_ + c) * 9 + j] * s;
        }
        Whp[idx] = (_Float16)v;
    } else if (idx < 87104) {
        int i = idx - 81920; int ce = i / 9;
        float s = gg[ce] * rsqrtf(gv[ce] + EPSF);
        ws[WS_WFOLD + i] = gen_w[i] * s;
    } else if (idx < 87680) {
        int ce = idx - 87104;
        float s = gg[ce] * rsqrtf(gv[ce] + EPSF);
        ws[WS_SHIFT + ce] = gb[ce] - gm[ce] * s;
    } else if (idx < 87808) {
        int oup = idx - 87680;
        float s = cg[oup] * rsqrtf(cv[oup] + EPSF);
        ws[WS_BIAS + oup] = cb[oup] - cm[oup] * s;
    }
}

// nb*1024 blocks: (bbl, p(64), cq(16)). Wave = one channel of the quad;
// thread = 4 px (rows r0+4i, col). Weights VGPR-resident (wv[81]+sh9[9],
// copied once from LDS, static indexing — v3-proven). Dense 1KB/wave cell
// stores; j8 cross-channel cell assembled via 2KB LDS; per-wave stats
// shuffle-reduced straight to part[] (no cross-wave reduce needed).
__global__ __launch_bounds__(256) void k_conv(
    const float* __restrict__ x, float* __restrict__ ws, int b0)
{
    __shared__ float xs[4][18 * 19];
    __shared__ float wfl[4][96];            // [ch][0..80] wfold, [84..92] shift
    __shared__ unsigned short j8l[4][256];
    int bid = blockIdx.x;
    int cq = bid & 15, p = (bid >> 4) & 63, bbl = bid >> 10;
    int b = b0 + bbl;
    int oh0 = (p >> 3) << 4, ow0 = (p & 7) << 4;
    int t = threadIdx.x;

    for (int i = t; i < 1296; i += 256) {
        int ch = i / 324, rr = i - ch * 324;
        int r = rr / 18, cc = rr - r * 18;
        int yy = oh0 + r - 1, xx = ow0 + cc - 1;
        float v = 0.f;
        if (yy >= 0 && yy < 128 && xx >= 0 && xx < 128)
            v = x[(size_t)(b * C_ + cq * 4 + ch) * HW_ + yy * 128 + xx];
        xs[ch][r * 19 + cc] = v;
    }
    for (int i = t; i < 384; i += 256) {
        int ch = i / 96, k = i - ch * 96;
        int c = cq * 4 + ch;
        float v = 0.f;
        if (k < 81) v = ws[WS_WFOLD + c * 81 + k];
        else if (k >= 84 && k < 93) v = ws[WS_SHIFT + c * 9 + (k - 84)];
        wfl[ch][k] = v;
    }
    __syncthreads();

    int w = __builtin_amdgcn_readfirstlane(t >> 6);   // wave id = channel in quad
    int lane = t & 63, r0 = lane >> 4, col = lane & 15;

    // ---- weights -> VGPRs, once, static-indexed
    float wv[81], sh9[9];
#pragma unroll
    for (int i = 0; i < 20; ++i) {
        float4 v4 = *(const float4*)&wfl[w][i * 4];
        wv[i * 4] = v4.x; wv[i * 4 + 1] = v4.y; wv[i * 4 + 2] = v4.z; wv[i * 4 + 3] = v4.w;
    }
    wv[80] = wfl[w][80];
#pragma unroll
    for (int i = 0; i < 9; ++i) sh9[i] = wfl[w][84 + i];

    float st0 = 0.f, st1 = 0.f;
    int kbBase = (cq >> 1) * 10 + (cq & 1) * 5;
    int tileBase = ((p >> 3) * 2) * 8 + (p & 7);
    _Float16* Bimg = (_Float16*)(ws + WS_BIMG) + (size_t)bbl * BIMG_BATCH_F16;

#pragma unroll 1
    for (int i = 0; i < 4; ++i) {
        int row16 = r0 + 4 * i;
        float nb[9];
#pragma unroll
        for (int dy = 0; dy < 3; ++dy)
#pragma unroll
            for (int dx = 0; dx < 3; ++dx)
                nb[dy * 3 + dx] = xs[w][(row16 + dy) * 19 + col + dx];
        float uv[9];
#pragma unroll
        for (int j = 0; j < 9; ++j) uv[j] = sh9[j];
#pragma unroll
        for (int k = 0; k < 9; ++k) {
            float xv = nb[k];
#pragma unroll
            for (int j = 0; j < 9; ++j) uv[j] = fmaf(wv[j * 9 + k], xv, uv[j]);
        }
#pragma unroll
        for (int j = 0; j < 9; ++j) {
            float v = fmaxf(uv[j], 0.f);
            uv[j] = v;
            st0 += v;
            st1 = fmaf(v, v, st1);
        }
        int tile = tileBase + (row16 >> 3) * 8;
        int px = (row16 & 7) * 16 + col;
        uint4 oc;
        oc.x = pk_u32(uv[0], uv[1]); oc.y = pk_u32(uv[2], uv[3]);
        oc.z = pk_u32(uv[4], uv[5]); oc.w = pk_u32(uv[6], uv[7]);
        *(uint4*)(Bimg + (size_t)(tile * KB_ + kbBase + w) * 1024 + (size_t)px * 8) = oc;
        _Float16 h8 = (_Float16)uv[8];
        j8l[w][row16 * 16 + col] = __builtin_bit_cast(unsigned short, h8);
    }
    __syncthreads();

    {   // ---- cell kbBase+4: {ch0 j8, ch1 j8, ch2 j8, ch3 j8, 0,0,0,0}
        int row16 = t >> 4;
        int tile = tileBase + (row16 >> 3) * 8;
        int px = t & 127;
        uint4 oc;
        oc.x = (unsigned int)j8l[0][t] | ((unsigned int)j8l[1][t] << 16);
        oc.y = (unsigned int)j8l[2][t] | ((unsigned int)j8l[3][t] << 16);
        oc.z = 0u; oc.w = 0u;
        *(uint4*)(Bimg + (size_t)(tile * KB_ + kbBase + 4) * 1024 + (size_t)px * 8) = oc;
    }

    // ---- stats: wave = channel, shuffle reduce, lane0 writes part directly
#pragma unroll
    for (int off = 32; off > 0; off >>= 1) {
        st0 += __shfl_down(st0, off, 64);
        st1 += __shfl_down(st1, off, 64);
    }
    if (lane == 0) {
        float* part = ws + WS_PART;
        part[(size_t)((b * 16 + cq) * 8 + w * 2) * 64 + p] = st0;
        part[(size_t)((b * 16 + cq) * 8 + w * 2 + 1) * 64 + p] = st1;
    }
}

__global__ __launch_bounds__(256) void k_gate(
    const float* __restrict__ part,
    const float* __restrict__ cwt, const float* __restrict__ cbs,
    const float* __restrict__ swt, const float* __restrict__ sbs,
    const float* __restrict__ gnw, const float* __restrict__ gnb,
    const float* __restrict__ wadd, float4* __restrict__ gate, int b0, int nb)
{
    int i = blockIdx.x * 256 + threadIdx.x;
    if (i >= nb * 64) return;
    int b = b0 + (i >> 6), c = i & 63;
    const float* pp = part + (size_t)((b * 16 + (c >> 2)) * 8 + (c & 3) * 2) * 64;
    float s1 = 0.f, s2 = 0.f;
#pragma unroll
    for (int q = 0; q < 16; ++q) {
        float4 a = *(const float4*)(pp + q * 4);
        float4 d = *(const float4*)(pp + 64 + q * 4);
        s1 += a.x + a.y + a.z + a.w;
        s2 += d.x + d.y + d.z + d.w;
    }
    const float N = 9.f * 16384.f;
    float mean = s1 / N;
    float var = s2 / N - mean * mean;
    float inv = rsqrtf(var + EPSF);
    int cgi = c & 7;
    float wa = wadd[0];
    float cgt = sigmf(cwt[cgi] * mean + cbs[cgi]);
    const float NL2E = -1.44269504f;   // sigm(t)=rcp(1+exp2(-t*log2e))
    float4 o;
    o.x = wa * cgt;
    o.y = 1.f - wa;
    o.z = NL2E * (swt[cgi] * gnw[cgi] * inv);
    o.w = NL2E * (swt[cgi] * (gnb[cgi] - mean * inv * gnw[cgi]) + sbs[cgi]);
    gate[b * 64 + c] = o;
}

// nb*256 blocks: (bbl, tile, half). M=128 oup x N=64 px, K=640 in 2 rounds of
// 40 cells. Staging gates the pre-gate B-image into kb-major LDS Bs[40][64][8]
// (40KB). v9 map: gate params cell-uniform for cl<4 cells (one float4);
// cl==4 cells gate only e0..3 (e4..7 pads stay 0). MFMA/epilogue unchanged.
__global__ __launch_bounds__(256, 4) void k_main(
    const float* __restrict__ ws, float* __restrict__ out, int b0)
{
    __shared__ _Float16 Bs[40 * 512];      // [kl][px(64)][8] = 40 KB
    int t = threadIdx.x;
    int bid = blockIdx.x;
    int half = bid & 1, tile = (bid >> 1) & 127, bbl = bid >> 8;
    int b = b0 + bbl;
    int oh0 = (tile >> 3) << 3, ow0 = (tile & 7) << 4;

    int w = __builtin_amdgcn_readfirstlane(t >> 6);
    int lane = t & 63, quad = lane >> 4, l15 = lane & 15;

    const _Float16* Wh = (const _Float16*)(ws + WS_WH);
    const _Float16* Bimg = (const _Float16*)(ws + WS_BIMG)
        + (size_t)bbl * BIMG_BATCH_F16 + (size_t)tile * (KB_ * 1024)
        + (size_t)(half * 64 + lane) * 8;
    const float4* gp = (const float4*)(ws + WS_GATE) + b * 64;

    v4f acc[2][4];
#pragma unroll
    for (int a = 0; a < 2; ++a)
#pragma unroll
        for (int bb = 0; bb < 4; ++bb) acc[a][bb] = (v4f)0.f;

#pragma unroll 1
    for (int r = 0; r < 2; ++r) {
        if (r) __syncthreads();            // MFMA of prev round done reading Bs
        // ---- stage + gate: 40 cells, 10 per wave, 1KB/wave coalesced loads
#pragma unroll 2
        for (int i = 0; i < 10; ++i) {
            int kl = i * 4 + w;            // wave-uniform LDS cell
            int kb = r * 40 + kl;          // wave-uniform global cell
            int grp = kb / 10, rr = kb - grp * 10;
            int tp = (rr >= 5) ? 1 : 0, cl = rr - tp * 5;
            int cbase = grp * 8 + tp * 4;
            uint4 cell = *(const uint4*)(Bimg + (size_t)kb * 1024);
            v8h v = __builtin_bit_cast(v8h, cell);
            uint4 oc;
            if (cl < 4) {                  // wave-uniform branch
                float4 g = gp[cbase + cl];
                float u[8];
#pragma unroll
                for (int e = 0; e < 8; ++e) {
                    float f = (float)v[e];
                    float ex = __builtin_amdgcn_exp2f(fmaf(g.z, f, g.w));
                    u[e] = f * fmaf(g.y, __builtin_amdgcn_rcpf(1.f + ex), g.x);
                }
                oc.x = pk_u32(u[0], u[1]); oc.y = pk_u32(u[2], u[3]);
                oc.z = pk_u32(u[4], u[5]); oc.w = pk_u32(u[6], u[7]);
            } else {                       // j8 cell: e0..3 channels, e4..7 pads
                float4 g0 = gp[cbase], g1 = gp[cbase + 1];
                float4 g2 = gp[cbase + 2], g3 = gp[cbase + 3];
                float u[4];
#pragma unroll
                for (int e = 0; e < 4; ++e) {
                    float f = (float)v[e];
                    float4 g = (e == 0) ? g0 : ((e == 1) ? g1 : ((e == 2) ? g2 : g3));
                    float ex = __builtin_amdgcn_exp2f(fmaf(g.z, f, g.w));
                    u[e] = f * fmaf(g.y, __builtin_amdgcn_rcpf(1.f + ex), g.x);
                }
                oc.x = pk_u32(u[0], u[1]); oc.y = pk_u32(u[2], u[3]);
                oc.z = 0u; oc.w = 0u;
            }
            *(uint4*)(Bs + kl * 512 + lane * 8) = oc;   // contiguous 1KB/wave
        }
        __syncthreads();
        // ---- MFMA: 10 K-steps of 32; A from L2-hot Wh, B from LDS
#pragma unroll
        for (int s = 0; s < 10; ++s) {
            int cglob = r * 40 + s * 4 + quad;
            const _Float16* Ap = Wh + ((size_t)cglob * 128 + w * 32 + l15) * 8;
            v8h A0 = *(const v8h*)(Ap);
            v8h A1 = *(const v8h*)(Ap + 128);          // +16 oup rows
            int klq = s * 4 + quad;
            v8h Bf[4];
#pragma unroll
            for (int bb = 0; bb < 4; ++bb)
                Bf[bb] = *(const v8h*)(Bs + klq * 512 + (bb * 16 + l15) * 8);
#pragma unroll
            for (int bb = 0; bb < 4; ++bb) {
                acc[0][bb] = __builtin_amdgcn_mfma_f32_16x16x32_f16(A0, Bf[bb], acc[0][bb], 0, 0, 0);
                acc[1][bb] = __builtin_amdgcn_mfma_f32_16x16x32_f16(A1, Bf[bb], acc[1][bb], 0, 0, 0);
            }
        }
    }

    // ---- epilogue: bias + SiLU; C/D: col=lane&15(px), row=quad*4+reg(oup)
    size_t ob = (size_t)b * 128 * HW_;
#pragma unroll
    for (int a = 0; a < 2; ++a) {
#pragma unroll
        for (int r2 = 0; r2 < 4; ++r2) {
            int oup = w * 32 + a * 16 + quad * 4 + r2;
            float bo = ws[WS_BIAS + oup];
#pragma unroll
            for (int bb = 0; bb < 4; ++bb) {
                int p2 = half * 64 + bb * 16 + l15;
                int py2 = p2 >> 4, px2 = p2 & 15;
                float z = acc[a][bb][r2] + bo;
                out[ob + (size_t)oup * HW_ + (oh0 + py2) * W_ + ow0 + px2] = z * sigmf(z);
            }
        }
    }
}

extern "C" void kernel_launch(void* const* d_in, const int* in_sizes, int n_in,
                              void* d_out, int out_size, void* d_ws, size_t ws_size,
                              hipStream_t stream)
{
    const float* x      = (const float*)d_in[0];
    const float* gen_w  = (const float*)d_in[1];
    const float* gg     = (const float*)d_in[2];
    const float* gb     = (const float*)d_in[3];
    const float* gm     = (const float*)d_in[4];
    const float* gv     = (const float*)d_in[5];
    const float* gnw    = (const float*)d_in[6];
    const float* gnb    = (const float*)d_in[7];
    const float* cwt    = (const float*)d_in[8];
    const float* cbs    = (const float*)d_in[9];
    const float* swt    = (const float*)d_in[10];
    const float* sbs    = (const float*)d_in[11];
    const float* wadd   = (const float*)d_in[12];
    const float* conv_w = (const float*)d_in[13];
    const float* cg2    = (const float*)d_in[14];
    const float* cb2    = (const float*)d_in[15];
    const float* cm2    = (const float*)d_in[16];
    const float* cv2    = (const float*)d_in[17];
    float* ws  = (float*)d_ws;
    float* out = (float*)d_out;

    // pick the largest batch chunk whose B-image fits in ws
    size_t avail = ws_size / 4;   // floats
    int nb = 1;
    const int cands[4] = {8, 4, 2, 1};
    for (int i = 0; i < 4; ++i) {
        if ((size_t)WS_BIMG + (size_t)cands[i] * BIMG_BATCH_FLT <= avail) { nb = cands[i]; break; }
    }

    k_fold<<<343, 256, 0, stream>>>(gen_w, gg, gb, gm, gv, conv_w, cg2, cb2, cm2, cv2, ws);
    for (int b0 = 0; b0 < 8; b0 += nb) {
        k_conv<<<nb * 1024, 256, 0, stream>>>(x, ws, b0);
        k_gate<<<(nb * 64 + 255) / 256, 256, 0, stream>>>(
            ws + WS_PART, cwt, cbs, swt, sbs, gnw, gnb, wadd,
            (float4*)(ws + WS_GATE), b0, nb);
        k_main<<<nb * 256, 256, 0, stream>>>(ws, out, b0);
    }
}